// Round 5
// baseline (157.957 us; speedup 1.0000x reference)
//
#include <hip/hip_runtime.h>
#include <hip/hip_bf16.h>
#include <stdint.h>

// KAN-like regressor: N=65536, D=32 features, H=128.
// out[n] = sum_d ( relu( relu(x[n,d]*W1[d,:]+b1[d,:]) @ W2[d] ) . W3[d] + b3[d] )
//
// R4 (resubmit; previous bench died on container-acquire, not kernel):
// M2N2 wave split for occupancy (3 waves/SIMD target).
//  - wave (wm,wn): h_out half wm (64 m), row half wn (32 rows/iter of a 64-row tile)
//  - w2f persistent = 64 VGPR; h1 via K=2 MFMA fused into main loop (bfr transient)
//  - b2 seeded via rank-1 MFMA; scalar epilogue (fmax+fma vs LDS-broadcast W3),
//    one shfl_xor(32), one atomicAdd per row per wm half
//  - grid 768 = 3 blocks/CU; __launch_bounds__(256,3) caps regs at 170
//  - out zeroed by hipMemsetAsync; sum(b3) folded into (d==0,wm==0) epilogue

#define D_FEAT 32
#define H_DIM  128
#define SLOTS  24          // blocks per feature; grid = 32*24 = 768 = 3/CU
#define THREADS 256        // 4 waves: (wm,wn) in {0,1}^2
#define ROWTILES 1024      // N / 64
#define MAXT   43          // max tiles per block = ceil(1024/24)

typedef float    f32x16 __attribute__((ext_vector_type(16)));
typedef short    bf16x8 __attribute__((ext_vector_type(8)));
typedef uint32_t u32;

static __device__ __forceinline__ u32 cvtpk(float lo, float hi) {
    u32 r;
    asm("v_cvt_pk_bf16_f32 %0, %1, %2" : "=v"(r) : "v"(lo), "v"(hi));
    return r;
}
static __device__ __forceinline__ bf16x8 frag4(u32 a, u32 b, u32 c, u32 d) {
    int4 t = make_int4((int)a, (int)b, (int)c, (int)d);
    return __builtin_bit_cast(bf16x8, t);
}
static __device__ __forceinline__ bf16x8 frag1(u32 a) { return frag4(a, 0u, 0u, 0u); }

#define MFMA32(A, B, C) __builtin_amdgcn_mfma_f32_32x32x16_bf16((A), (B), (C), 0, 0, 0)

// relu + pack 8 consecutive D-regs (half s) into one B-frag; s is unroll-const.
static __device__ __forceinline__ bf16x8 relu_pack(const f32x16& v, int s) {
    u32 c0 = cvtpk(fmaxf(v[8*s+0], 0.f), fmaxf(v[8*s+1], 0.f));
    u32 c1 = cvtpk(fmaxf(v[8*s+2], 0.f), fmaxf(v[8*s+3], 0.f));
    u32 c2 = cvtpk(fmaxf(v[8*s+4], 0.f), fmaxf(v[8*s+5], 0.f));
    u32 c3 = cvtpk(fmaxf(v[8*s+6], 0.f), fmaxf(v[8*s+7], 0.f));
    return frag4(c0, c1, c2, c3);
}

__global__ __launch_bounds__(THREADS, 3) void kan_main(
    const float* __restrict__ x,    // [N, 32]
    const float* __restrict__ W1,   // [32, 128]
    const float* __restrict__ b1,   // [32, 128]
    const float* __restrict__ W2,   // [32, 128, 128]  (h_in, h_out) per d
    const float* __restrict__ b2,   // [32, 128]
    const float* __restrict__ W3,   // [32, 128]
    const float* __restrict__ b3,   // [32]
    float* __restrict__ out)        // [N]
{
    __shared__ float xall[MAXT * 64];   // 10.75 KB
    __shared__ float W3s[H_DIM];

    const int tid   = threadIdx.x;
    const int d     = blockIdx.x / SLOTS;
    const int bslot = blockIdx.x % SLOTS;
    const int w     = tid >> 6;
    const int wm    = w >> 1;          // h_out half: m in [64*wm, 64*wm+64)
    const int wn    = w & 1;           // row half of each 64-row tile
    const int l     = tid & 63;
    const int l31   = l & 31;
    const int g     = l >> 5;

    // tiles this block handles: rowtile = bslot + SLOTS*it < 1024
    const int ntile = (ROWTILES - 1 - bslot) / SLOTS + 1;   // 42 or 43

    // ---- preload x (this block's rows, column d) ----
    for (int idx = tid; idx < ntile * 64; idx += THREADS) {
        int tl = idx >> 6;
        xall[idx] = x[(size_t)((bslot + SLOTS * tl) * 64 + (idx & 63)) * D_FEAT + d];
    }
    if (tid < H_DIM) W3s[tid] = W3[d * H_DIM + tid];

    // sum(b3): uniform scalar chain (folded into d==0,wm==0 epilogue)
    float b3s = 0.f;
#pragma unroll
    for (int k = 0; k < D_FEAT; ++k) b3s += b3[k];

    // per-lane h1 A-operand (W1,b1 at k=0,1; group-0 lanes only) and b2 seeds
    const int mo0 = 2 * wm, mo1 = 2 * wm + 1;
    u32 w1b1[4], b2w[2];
#pragma unroll
    for (int mt = 0; mt < 4; ++mt) {
        int m = 32 * mt + l31;
        u32 v = cvtpk(W1[d * H_DIM + m], b1[d * H_DIM + m]);
        w1b1[mt] = g ? 0u : v;
    }
    b2w[0] = g ? 0u : cvtpk(b2[d * H_DIM + 32 * mo0 + l31], 0.f);
    b2w[1] = g ? 0u : cvtpk(b2[d * H_DIM + 32 * mo1 + l31], 0.f);
    const bf16x8 onesB = frag1(g ? 0u : 0x00003F80u);   // bf16(1.0) at k=0

    // W2^T A-frags for this wave's 64 h_out: 64 VGPR persistent.
    // lane row m = 32*mo + l31; elem e -> k = 16*ks + 4*g + (e&3) + 8*(e>>2)
    bf16x8 w2f[2][8];
    {
        const float* W2d = W2 + (size_t)d * H_DIM * H_DIM;
#pragma unroll
        for (int j = 0; j < 2; ++j) {
            int mm = 32 * (mo0 + j) + l31;
#pragma unroll
            for (int ks = 0; ks < 8; ++ks) {
                u32 dw[4];
#pragma unroll
                for (int p = 0; p < 4; ++p) {
                    int e0 = 2 * p, e1 = 2 * p + 1;
                    int k0 = 16 * ks + 4 * g + (e0 & 3) + 8 * (e0 >> 2);
                    int k1 = 16 * ks + 4 * g + (e1 & 3) + 8 * (e1 >> 2);
                    dw[p] = cvtpk(W2d[(size_t)k0 * H_DIM + mm],
                                  W2d[(size_t)k1 * H_DIM + mm]);
                }
                w2f[j][ks] = frag4(dw[0], dw[1], dw[2], dw[3]);
            }
        }
    }
    __syncthreads();   // the only barrier

    const f32x16 zc = {};
    const bool addb3 = (d == 0) && (wm == 0);

    for (int it = 0; it < ntile; ++it) {
        const int rbase = (bslot + SLOTS * it) * 64 + 32 * wn;  // wave's 32 rows
        float xv = xall[it * 64 + 32 * wn + l31];
        bf16x8 Bx = frag1(g ? 0u : cvtpk(xv, 1.0f));

        // seed acc chains with b2 (rank-1 MFMA)
        f32x16 a0 = MFMA32(frag1(b2w[0]), onesB, zc);
        f32x16 a1 = MFMA32(frag1(b2w[1]), onesB, zc);

        // fused h1 + main GEMM: per mt, one h1-MFMA -> 2 packs -> 4 chain MFMAs
#pragma unroll
        for (int mt = 0; mt < 4; ++mt) {
            f32x16 d1 = MFMA32(frag1(w1b1[mt]), Bx, zc);
            bf16x8 bl = relu_pack(d1, 0);
            bf16x8 bh = relu_pack(d1, 1);
            a0 = MFMA32(w2f[0][2 * mt + 0], bl, a0);
            a1 = MFMA32(w2f[1][2 * mt + 0], bl, a1);
            a0 = MFMA32(w2f[0][2 * mt + 1], bh, a0);
            a1 = MFMA32(w2f[1][2 * mt + 1], bh, a1);
        }

        // scalar epilogue: rs = sum over wave's 64 m of relu(h2[m])*W3[m]
        // acc reg r <-> m = 32*mo + (r&3) + 8*(r>>2) + 4*g
        float rs = 0.f;
#pragma unroll
        for (int q = 0; q < 4; ++q) {
            const float4 w3a = *reinterpret_cast<const float4*>(&W3s[32 * mo0 + 4 * g + 8 * q]);
            const float4 w3b = *reinterpret_cast<const float4*>(&W3s[32 * mo1 + 4 * g + 8 * q]);
            rs += fmaxf(a0[4 * q + 0], 0.f) * w3a.x;
            rs += fmaxf(a0[4 * q + 1], 0.f) * w3a.y;
            rs += fmaxf(a0[4 * q + 2], 0.f) * w3a.z;
            rs += fmaxf(a0[4 * q + 3], 0.f) * w3a.w;
            rs += fmaxf(a1[4 * q + 0], 0.f) * w3b.x;
            rs += fmaxf(a1[4 * q + 1], 0.f) * w3b.y;
            rs += fmaxf(a1[4 * q + 2], 0.f) * w3b.z;
            rs += fmaxf(a1[4 * q + 3], 0.f) * w3b.w;
        }
        rs += __shfl_xor(rs, 32, 64);      // combine g halves (m +- 4)
        if (addb3) rs += b3s;              // fold sum(b3) exactly once per row
        if (!g) atomicAdd(&out[rbase + l31], rs);
    }
}

extern "C" void kernel_launch(void* const* d_in, const int* in_sizes, int n_in,
                              void* d_out, int out_size, void* d_ws, size_t ws_size,
                              hipStream_t stream) {
    const float* x  = (const float*)d_in[0];
    const float* W1 = (const float*)d_in[1];
    const float* b1 = (const float*)d_in[2];
    const float* W2 = (const float*)d_in[3];
    const float* b2 = (const float*)d_in[4];
    const float* W3 = (const float*)d_in[5];
    const float* b3 = (const float*)d_in[6];
    float* out = (float*)d_out;
    const int N = in_sizes[0] / D_FEAT;   // 65536

    hipMemsetAsync(out, 0, (size_t)N * sizeof(float), stream);
    kan_main<<<D_FEAT * SLOTS, THREADS, 0, stream>>>(x, W1, b1, W2, b2, W3, b3, out);
}